// Round 7
// baseline (245.056 us; speedup 1.0000x reference)
//
#include <hip/hip_runtime.h>
#include <hip/hip_bf16.h>

#define B_   8
#define LQ_  2048
#define LK_  2048
#define D_   128
#define QBLK 64
#define THREADS 512
#define NITER 16                              // 128 keys per iteration
#define NEGL2E (-0.12755004910797864f)        // -log2(e)/sqrt(128)

typedef __attribute__((ext_vector_type(8))) __bf16 bf16x8;  // MFMA A/B frag
typedef __attribute__((ext_vector_type(4))) float  f32x4;   // MFMA C/D frag
typedef __attribute__((ext_vector_type(4))) float  fx4;
typedef __attribute__((ext_vector_type(4))) int    i32x4;

// ---------- prep: mask int32 -> 1 bit/key, linear layout ----------
// byte t covers keys 8t..8t+7 of the flattened [b][q][k] mask; bit j = (m!=0).
// Main-loop view: packed[(b*2048+q)*256 + i*16 + kq*4] as u32 holds bits
// (key & 31) for keys i*128 + kq*32 .. +31.   Reads+writes fully coalesced.
__global__ __launch_bounds__(256)
void mprep(const int* __restrict__ mask, unsigned char* __restrict__ mp)
{
    size_t t = (size_t)blockIdx.x * 256 + threadIdx.x;     // 0..4194303
    const int* src = mask + t * 8;
    i32x4 a = *(const i32x4*)src;
    i32x4 c = *(const i32x4*)(src + 4);
    unsigned int v = 0;
    v |= (a[0] != 0 ? 1u : 0u);
    v |= (a[1] != 0 ? 2u : 0u);
    v |= (a[2] != 0 ? 4u : 0u);
    v |= (a[3] != 0 ? 8u : 0u);
    v |= (c[0] != 0 ? 16u : 0u);
    v |= (c[1] != 0 ? 32u : 0u);
    v |= (c[2] != 0 ? 64u : 0u);
    v |= (c[3] != 0 ? 128u : 0u);
    mp[t] = (unsigned char)v;
}

// ---------- prep: K and V -> fragment-packed bf16 (fused) ----------
// K frag f=((b*128+kk)*4+dblk): lane(l15,g) = K[kk*16+l15][dblk*32+g*8..+7]
// V frag f=((b*64+ck)*8+nb), slot-permuted: elem e = V[ck*32+(e>>2)*16+g*4+(e&3)][nb*16+l15]
__global__ __launch_bounds__(256)
void kvprep(const float* __restrict__ k, const float* __restrict__ v,
            __bf16* __restrict__ kp, __bf16* __restrict__ vp)
{
    int id = blockIdx.x * 256 + threadIdx.x;          // 0..524287
    if (id < 262144) {
        int lane = id & 63;
        int f    = id >> 6;                           // 0..4095
        int dblk = f & 3, kk = (f >> 2) & 127, b = f >> 9;
        const float* src = k + ((size_t)b * LK_ + kk * 16 + (lane & 15)) * D_
                             + dblk * 32 + (lane >> 4) * 8;
        fx4 f0 = *(const fx4*)src;
        fx4 f1 = *(const fx4*)(src + 4);
        bf16x8 w;
#pragma unroll
        for (int j = 0; j < 4; ++j) { w[j] = (__bf16)f0[j]; w[4 + j] = (__bf16)f1[j]; }
        *(bf16x8*)(kp + (size_t)f * 512 + lane * 8) = w;
    } else {
        int id2  = id - 262144;
        int lane = id2 & 63;
        int f    = id2 >> 6;
        int nb = f & 7, ck = (f >> 3) & 63, b = f >> 9;
        int l15 = lane & 15, g = lane >> 4;
        bf16x8 w;
#pragma unroll
        for (int e = 0; e < 8; ++e) {
            int key = ck * 32 + (e >> 2) * 16 + g * 4 + (e & 3);
            w[e] = (__bf16)v[((size_t)b * LK_ + key) * D_ + nb * 16 + l15];
        }
        *(bf16x8*)(vp + (size_t)f * 512 + lane * 8) = w;
    }
}

// ---------- main: barrier-free, all loop traffic L2-resident ----------
// 8 waves: qg = wid&1 (32 q rows), kq = wid>>1 (32-key quarter per 128-key iter).
// K/V loads = contiguous 1KB bursts; mask = 2 u32/lane/iter from packed bits.
__global__ __launch_bounds__(THREADS, 2)
void sigattn_main(const float* __restrict__ q, const unsigned char* __restrict__ mp,
                  const __bf16* __restrict__ Kp, const __bf16* __restrict__ Vp,
                  float* __restrict__ out)
{
    __shared__ float red[64 * 132];                   // epilogue only

    const int tid  = threadIdx.x;
    const int lane = tid & 63;
    const int l15  = lane & 15;
    const int g    = lane >> 4;
    const int wid  = tid >> 6;
    const int qg   = wid & 1;
    const int kq   = wid >> 1;                        // 0..3
    const int qbase = qg * 32;

    const int bid = blockIdx.x;
    const int b   = bid & 7;                          // batch -> XCD-pinned K/V/mask
    const int q0  = (bid >> 3) * QBLK;

    const float*         qb  = q  + ((size_t)b * LQ_ + q0) * D_;
    const unsigned char* mpb = mp + ((size_t)b * LQ_ + q0) * 256;
    const __bf16*        kp  = Kp + (size_t)b * 262144;
    const __bf16*        vp  = Vp + (size_t)b * 262144;
    float*               ob  = out + ((size_t)b * LQ_ + q0) * D_;

    // Q fragments (registers for whole kernel)
    bf16x8 qfrag[2][4];
#pragma unroll
    for (int qq = 0; qq < 2; ++qq) {
        const float* qrow = qb + (size_t)(qbase + qq * 16 + l15) * D_;
#pragma unroll
        for (int dblk = 0; dblk < 4; ++dblk) {
            fx4 f0 = *(const fx4*)(qrow + dblk * 32 + g * 8);
            fx4 f1 = *(const fx4*)(qrow + dblk * 32 + g * 8 + 4);
            bf16x8 w;
#pragma unroll
            for (int j = 0; j < 4; ++j) { w[j] = (__bf16)f0[j]; w[4 + j] = (__bf16)f1[j]; }
            qfrag[qq][dblk] = w;
        }
    }

    // per-lane packed-mask addresses (u32 covering this lane's 32-key quarter)
    const unsigned char* maddr[2];
#pragma unroll
    for (int qq = 0; qq < 2; ++qq)
        maddr[qq] = mpb + (size_t)(qbase + qq * 16 + l15) * 256 + kq * 4;

    // iter-0 K fragments + mask words
    bf16x8 Kc[2][4];
#pragma unroll
    for (int ksl = 0; ksl < 2; ++ksl)
#pragma unroll
        for (int dblk = 0; dblk < 4; ++dblk)
            Kc[ksl][dblk] = *(const bf16x8*)(kp + (size_t)((kq * 2 + ksl) * 4 + dblk) * 512 + lane * 8);
    unsigned int mc[2];
#pragma unroll
    for (int qq = 0; qq < 2; ++qq) mc[qq] = *(const unsigned int*)(maddr[qq]);

    f32x4 oacc[2][8];
#pragma unroll
    for (int qq = 0; qq < 2; ++qq)
#pragma unroll
        for (int nb = 0; nb < 8; ++nb) oacc[qq][nb] = (f32x4){0.f, 0.f, 0.f, 0.f};

#pragma unroll 2
    for (int i = 0; i < NITER; ++i) {
        const bool more = (i + 1 < NITER);

        // ---- V fragments for this iter (issued early; consumed after sigmoid) ----
        bf16x8 vfr[8];
#pragma unroll
        for (int nb = 0; nb < 8; ++nb)
            vfr[nb] = *(const bf16x8*)(vp + (size_t)((i * 4 + kq) * 8 + nb) * 512 + lane * 8);

        // ---- prefetch iter i+1: K fragments + mask words (L2) ----
        bf16x8 Kn[2][4];
        unsigned int mn[2];
        if (more) {
#pragma unroll
            for (int ksl = 0; ksl < 2; ++ksl)
#pragma unroll
                for (int dblk = 0; dblk < 4; ++dblk)
                    Kn[ksl][dblk] = *(const bf16x8*)(kp + (size_t)(((i + 1) * 8 + kq * 2 + ksl) * 4 + dblk) * 512 + lane * 8);
#pragma unroll
            for (int qq = 0; qq < 2; ++qq)
                mn[qq] = *(const unsigned int*)(maddr[qq] + (i + 1) * 16);
        }

        // ---- QK^T swapped: sacc[qq][ksl] (rows=keys, cols=q) ----
        f32x4 sacc[2][2];
#pragma unroll
        for (int qq = 0; qq < 2; ++qq)
#pragma unroll
            for (int ksl = 0; ksl < 2; ++ksl) sacc[qq][ksl] = (f32x4){0.f, 0.f, 0.f, 0.f};
#pragma unroll
        for (int ksl = 0; ksl < 2; ++ksl)
#pragma unroll
            for (int dblk = 0; dblk < 4; ++dblk) {
                bf16x8 a = Kc[ksl][dblk];
#pragma unroll
                for (int qq = 0; qq < 2; ++qq)
                    sacc[qq][ksl] = __builtin_amdgcn_mfma_f32_16x16x32_bf16(a, qfrag[qq][dblk], sacc[qq][ksl], 0, 0, 0);
            }

        // ---- mask bits + sigmoid -> P fragments (registers only) ----
        bf16x8 pfrag[2];
#pragma unroll
        for (int qq = 0; qq < 2; ++qq) {
#pragma unroll
            for (int ksl = 0; ksl < 2; ++ksl) {
                const unsigned int bb = (mc[qq] >> (ksl * 16 + 4 * g)) & 0xFu;
#pragma unroll
                for (int r = 0; r < 4; ++r) {
                    float e = exp2f(sacc[qq][ksl][r] * NEGL2E);
                    float p = __builtin_amdgcn_rcpf(1.0f + e);
                    p = ((bb >> r) & 1u) ? 0.0f : p;
                    pfrag[qq][ksl * 4 + r] = (__bf16)p;
                }
            }
        }

        // ---- PV (slot-permuted Vp matches pfrag ordering) ----
#pragma unroll
        for (int nb = 0; nb < 8; ++nb)
#pragma unroll
            for (int qq = 0; qq < 2; ++qq)
                oacc[qq][nb] = __builtin_amdgcn_mfma_f32_16x16x32_bf16(pfrag[qq], vfr[nb], oacc[qq][nb], 0, 0, 0);

        // ---- rotate prefetch (renamed away by unroll 2) ----
        if (more) {
#pragma unroll
            for (int ksl = 0; ksl < 2; ++ksl)
#pragma unroll
                for (int dblk = 0; dblk < 4; ++dblk)
                    Kc[ksl][dblk] = Kn[ksl][dblk];
            mc[0] = mn[0]; mc[1] = mn[1];
        }
    }

    // ---------------- epilogue: reduce the 4 kq partials, store ----------------
    __syncthreads();
    if (kq == 0) {
#pragma unroll
        for (int qq = 0; qq < 2; ++qq)
#pragma unroll
            for (int nb = 0; nb < 8; ++nb)
#pragma unroll
                for (int r = 0; r < 4; ++r)
                    red[(qbase + qq * 16 + 4 * g + r) * 132 + nb * 16 + l15] = oacc[qq][nb][r];
    }
    __syncthreads();
    if (kq == 1) {
#pragma unroll
        for (int qq = 0; qq < 2; ++qq)
#pragma unroll
            for (int nb = 0; nb < 8; ++nb)
#pragma unroll
                for (int r = 0; r < 4; ++r)
                    red[(qbase + qq * 16 + 4 * g + r) * 132 + nb * 16 + l15] += oacc[qq][nb][r];
    }
    __syncthreads();
    if (kq == 2) {
#pragma unroll
        for (int qq = 0; qq < 2; ++qq)
#pragma unroll
            for (int nb = 0; nb < 8; ++nb)
#pragma unroll
                for (int r = 0; r < 4; ++r)
                    red[(qbase + qq * 16 + 4 * g + r) * 132 + nb * 16 + l15] += oacc[qq][nb][r];
    }
    __syncthreads();
    if (kq == 3) {
#pragma unroll
        for (int qq = 0; qq < 2; ++qq)
#pragma unroll
            for (int nb = 0; nb < 8; ++nb)
#pragma unroll
                for (int r = 0; r < 4; ++r)
                    red[(qbase + qq * 16 + 4 * g + r) * 132 + nb * 16 + l15] += oacc[qq][nb][r];
    }
    __syncthreads();
#pragma unroll
    for (int i2 = 0; i2 < 4; ++i2) {
        int idx = tid + i2 * THREADS;
        int row = idx >> 5, c4 = idx & 31;
        fx4 val = *(const fx4*)(red + row * 132 + c4 * 4);
        __builtin_nontemporal_store(val, (fx4*)(ob + (size_t)row * D_ + c4 * 4));
    }
}

extern "C" void kernel_launch(void* const* d_in, const int* in_sizes, int n_in,
                              void* d_out, int out_size, void* d_ws, size_t ws_size,
                              hipStream_t stream) {
    const float* q    = (const float*)d_in[0];
    const float* k    = (const float*)d_in[1];
    const float* v    = (const float*)d_in[2];
    const int*   mask = (const int*)d_in[3];
    float*       out  = (float*)d_out;

    __bf16*        Kp = (__bf16*)d_ws;                             // 4 MB packed K frags
    __bf16*        Vp = (__bf16*)d_ws + (size_t)2097152;           // 4 MB packed V frags
    unsigned char* Mp = (unsigned char*)d_ws + (size_t)8388608;    // 4 MB packed mask bits

    mprep<<<dim3(16384), dim3(256), 0, stream>>>(mask, Mp);
    kvprep<<<dim3(2048), dim3(256), 0, stream>>>(k, v, Kp, Vp);
    sigattn_main<<<dim3(256), dim3(THREADS), 0, stream>>>(q, Mp, Kp, Vp, out);
}